// Round 15
// baseline (6262.098 us; speedup 1.0000x reference)
//
#include <hip/hip_runtime.h>
#include <hip/hip_bf16.h>
#include <math.h>

#define SLEN 2048
#define DDIM 512
#define BNUM 8
#define MTOT (BNUM * SLEN)   // 16384

typedef float f32x4 __attribute__((ext_vector_type(4)));
typedef short s16x8 __attribute__((ext_vector_type(8)));   // 8 bf16 (4 VGPRs)

// fp32 -> bf16 (RNE) as raw ushort
__device__ __forceinline__ unsigned short f2bf(float f) {
    unsigned u = __float_as_uint(f);
    u += 0x7FFFu + ((u >> 16) & 1u);
    return (unsigned short)(u >> 16);
}

// ---------------------------------------------------------------------------
// Device-scope (sc1) 8-byte access. Proven facts: sc0 = SE scope (stale
// cross-CU, r8); atomics-as-poll dirty L2 lines -> 7x HBM writeback and
// serialize (r13); issue+waitcnt of a comm load must be ONE asm block (r12).
// sc1 tagged {value, tag} slots remain the protocol (r4-r13 proven).
// ---------------------------------------------------------------------------
__device__ __forceinline__ void st_u64_sc1(uint2* p, uint2 v) {
    asm volatile("global_store_dwordx2 %0, %1, off sc1"
                 :: "v"(p), "v"(v) : "memory");
}
__device__ __forceinline__ uint2 ld_u64_sc1(const uint2* p) {
    uint2 v;
    asm volatile("global_load_dwordx2 %0, %1, off sc1\n\ts_waitcnt vmcnt(0)"
                 : "=v"(v) : "v"(p) : "memory");
    return v;
}

// ---------------------------------------------------------------------------
// Kernel 0: clear tag buffer through the SAME sc1 path the scan uses.
// ---------------------------------------------------------------------------
__global__ __launch_bounds__(512) void clear_tags_kernel(uint2* stateTag)
{
    int i = blockIdx.x * 512 + threadIdx.x;
    uint2 z; z.x = 0u; z.y = 0u;
    st_u64_sc1(&stateTag[i], z);
}

// ---------------------------------------------------------------------------
// Kernel A: fused precompute GEMM via bf16 MFMA (round-10, proven).
// ---------------------------------------------------------------------------
__global__ __launch_bounds__(256) void precompute_kernel(
    const float* __restrict__ x,
    const float* __restrict__ Wu, const float* __restrict__ bu,
    const float* __restrict__ Wa, const float* __restrict__ ba,
    const float* __restrict__ Wc, const float* __restrict__ bc,
    const float* __restrict__ Wg, const float* __restrict__ bg,
    float* __restrict__ gbuf, float* __restrict__ cosb,
    float* __restrict__ sinb, float* __restrict__ cdbuf,
    float* __restrict__ ogout)
{
    __shared__ unsigned short As[128 * 40];
    __shared__ unsigned short Bs[128 * 40];

    const int bn = blockIdx.x * 128;      // 0..1791 in steps of 128
    const int bm = blockIdx.y * 128;      // 0..16383

    const float* W; const float* bias; int mode; int dcol;
    if (bn < 512)       { W = Wu; bias = bu; mode = 0; dcol = bn; }
    else if (bn < 768)  { W = Wa; bias = ba; mode = 1; dcol = bn - 512; }
    else if (bn < 1280) { W = Wc; bias = bc; mode = 2; dcol = bn - 768; }
    else                { W = Wg; bias = bg; mode = 3; dcol = bn - 1280; }

    const int tid  = threadIdx.x;
    const int lane = tid & 63, wv = tid >> 6;
    const int wm = wv >> 1, wn = wv & 1;
    const int lr  = lane & 15;
    const int lkb = (lane >> 4) * 8;      // ushort offset of the 8-k group

    f32x4 acc[4][4];
    #pragma unroll
    for (int i = 0; i < 4; ++i)
        #pragma unroll
        for (int j = 0; j < 4; ++j)
            acc[i][j] = (f32x4){0.f, 0.f, 0.f, 0.f};

    const int r = tid >> 1, h = tid & 1;  // staging: row, k-half
    const float* aSrc = x + (size_t)(bm + r) * DDIM + h * 16;
    const float* bSrc = W + (size_t)(dcol + r) * DDIM + h * 16;
    unsigned short* aDst = &As[r * 40 + h * 16];
    unsigned short* bDst = &Bs[r * 40 + h * 16];

    for (int kt = 0; kt < 16; ++kt) {
        {
            float4 fa0 = *(const float4*)(aSrc + 0);
            float4 fa1 = *(const float4*)(aSrc + 4);
            float4 fa2 = *(const float4*)(aSrc + 8);
            float4 fa3 = *(const float4*)(aSrc + 12);
            union { unsigned short u[8]; s16x8 v; } pa0, pa1;
            pa0.u[0]=f2bf(fa0.x); pa0.u[1]=f2bf(fa0.y); pa0.u[2]=f2bf(fa0.z); pa0.u[3]=f2bf(fa0.w);
            pa0.u[4]=f2bf(fa1.x); pa0.u[5]=f2bf(fa1.y); pa0.u[6]=f2bf(fa1.z); pa0.u[7]=f2bf(fa1.w);
            pa1.u[0]=f2bf(fa2.x); pa1.u[1]=f2bf(fa2.y); pa1.u[2]=f2bf(fa2.z); pa1.u[3]=f2bf(fa2.w);
            pa1.u[4]=f2bf(fa3.x); pa1.u[5]=f2bf(fa3.y); pa1.u[6]=f2bf(fa3.z); pa1.u[7]=f2bf(fa3.w);
            *(s16x8*)(aDst + 0) = pa0.v;
            *(s16x8*)(aDst + 8) = pa1.v;

            float4 fb0 = *(const float4*)(bSrc + 0);
            float4 fb1 = *(const float4*)(bSrc + 4);
            float4 fb2 = *(const float4*)(bSrc + 8);
            float4 fb3 = *(const float4*)(bSrc + 12);
            union { unsigned short u[8]; s16x8 v; } pb0, pb1;
            pb0.u[0]=f2bf(fb0.x); pb0.u[1]=f2bf(fb0.y); pb0.u[2]=f2bf(fb0.z); pb0.u[3]=f2bf(fb0.w);
            pb0.u[4]=f2bf(fb1.x); pb0.u[5]=f2bf(fb1.y); pb0.u[6]=f2bf(fb1.z); pb0.u[7]=f2bf(fb1.w);
            pb1.u[0]=f2bf(fb2.x); pb1.u[1]=f2bf(fb2.y); pb1.u[2]=f2bf(fb2.z); pb1.u[3]=f2bf(fb2.w);
            pb1.u[4]=f2bf(fb3.x); pb1.u[5]=f2bf(fb3.y); pb1.u[6]=f2bf(fb3.z); pb1.u[7]=f2bf(fb3.w);
            *(s16x8*)(bDst + 0) = pb0.v;
            *(s16x8*)(bDst + 8) = pb1.v;

            aSrc += 32; bSrc += 32;
        }
        __syncthreads();

        s16x8 af[4], bf[4];
        #pragma unroll
        for (int i = 0; i < 4; ++i)
            af[i] = *(const s16x8*)&As[(wm * 64 + i * 16 + lr) * 40 + lkb];
        #pragma unroll
        for (int j = 0; j < 4; ++j)
            bf[j] = *(const s16x8*)&Bs[(wn * 64 + j * 16 + lr) * 40 + lkb];
        #pragma unroll
        for (int i = 0; i < 4; ++i)
            #pragma unroll
            for (int j = 0; j < 4; ++j)
                acc[i][j] = __builtin_amdgcn_mfma_f32_16x16x32_bf16(
                    af[i], bf[j], acc[i][j], 0, 0, 0);
        __syncthreads();
    }

    // ---- epilogue: bias + activation ----
    const int orow = (lane >> 4) * 4;
    #pragma unroll
    for (int i = 0; i < 4; ++i) {
        #pragma unroll
        for (int j = 0; j < 4; ++j) {
            #pragma unroll
            for (int v = 0; v < 4; ++v) {
                int m  = bm + wm * 64 + i * 16 + orow + v;
                int nc = dcol + wn * 64 + j * 16 + lr;
                float val = acc[i][j][v] + bias[nc];
                if (mode == 0) {
                    gbuf[(size_t)m * 512 + nc] = 1.f / (1.f + expf(-val));
                } else if (mode == 1) {
                    cosb[(size_t)m * 256 + nc] = cosf(val);
                    sinb[(size_t)m * 256 + nc] = sinf(val);
                } else if (mode == 2) {
                    cdbuf[(size_t)m * 512 + nc] = tanhf(val);
                } else {
                    ogout[(size_t)m * 512 + nc] = 1.f / (1.f + expf(-val));
                }
            }
        }
    }
}

// 64-MAC dot of a register weight slice (prefix P -> P0..P15) with 64
// contiguous LDS floats at ST. NOTE: (P##N).x — the parens are required;
// `P##2.y` would paste against the pp-number token `2.y` (round-14 lesson).
#define DOT64(P, ST, OUT) { \
    f32x4 sv_; float q0_=0.f,q1_=0.f,q2_=0.f,q3_=0.f; \
    sv_=*(const f32x4*)((ST)+ 0); q0_=fmaf((P##0).x,sv_.x,q0_); q1_=fmaf((P##0).y,sv_.y,q1_); q2_=fmaf((P##0).z,sv_.z,q2_); q3_=fmaf((P##0).w,sv_.w,q3_); \
    sv_=*(const f32x4*)((ST)+ 4); q0_=fmaf((P##1).x,sv_.x,q0_); q1_=fmaf((P##1).y,sv_.y,q1_); q2_=fmaf((P##1).z,sv_.z,q2_); q3_=fmaf((P##1).w,sv_.w,q3_); \
    sv_=*(const f32x4*)((ST)+ 8); q0_=fmaf((P##2).x,sv_.x,q0_); q1_=fmaf((P##2).y,sv_.y,q1_); q2_=fmaf((P##2).z,sv_.z,q2_); q3_=fmaf((P##2).w,sv_.w,q3_); \
    sv_=*(const f32x4*)((ST)+12); q0_=fmaf((P##3).x,sv_.x,q0_); q1_=fmaf((P##3).y,sv_.y,q1_); q2_=fmaf((P##3).z,sv_.z,q2_); q3_=fmaf((P##3).w,sv_.w,q3_); \
    sv_=*(const f32x4*)((ST)+16); q0_=fmaf((P##4).x,sv_.x,q0_); q1_=fmaf((P##4).y,sv_.y,q1_); q2_=fmaf((P##4).z,sv_.z,q2_); q3_=fmaf((P##4).w,sv_.w,q3_); \
    sv_=*(const f32x4*)((ST)+20); q0_=fmaf((P##5).x,sv_.x,q0_); q1_=fmaf((P##5).y,sv_.y,q1_); q2_=fmaf((P##5).z,sv_.z,q2_); q3_=fmaf((P##5).w,sv_.w,q3_); \
    sv_=*(const f32x4*)((ST)+24); q0_=fmaf((P##6).x,sv_.x,q0_); q1_=fmaf((P##6).y,sv_.y,q1_); q2_=fmaf((P##6).z,sv_.z,q2_); q3_=fmaf((P##6).w,sv_.w,q3_); \
    sv_=*(const f32x4*)((ST)+28); q0_=fmaf((P##7).x,sv_.x,q0_); q1_=fmaf((P##7).y,sv_.y,q1_); q2_=fmaf((P##7).z,sv_.z,q2_); q3_=fmaf((P##7).w,sv_.w,q3_); \
    sv_=*(const f32x4*)((ST)+32); q0_=fmaf((P##8).x,sv_.x,q0_); q1_=fmaf((P##8).y,sv_.y,q1_); q2_=fmaf((P##8).z,sv_.z,q2_); q3_=fmaf((P##8).w,sv_.w,q3_); \
    sv_=*(const f32x4*)((ST)+36); q0_=fmaf((P##9).x,sv_.x,q0_); q1_=fmaf((P##9).y,sv_.y,q1_); q2_=fmaf((P##9).z,sv_.z,q2_); q3_=fmaf((P##9).w,sv_.w,q3_); \
    sv_=*(const f32x4*)((ST)+40); q0_=fmaf((P##10).x,sv_.x,q0_); q1_=fmaf((P##10).y,sv_.y,q1_); q2_=fmaf((P##10).z,sv_.z,q2_); q3_=fmaf((P##10).w,sv_.w,q3_); \
    sv_=*(const f32x4*)((ST)+44); q0_=fmaf((P##11).x,sv_.x,q0_); q1_=fmaf((P##11).y,sv_.y,q1_); q2_=fmaf((P##11).z,sv_.z,q2_); q3_=fmaf((P##11).w,sv_.w,q3_); \
    sv_=*(const f32x4*)((ST)+48); q0_=fmaf((P##12).x,sv_.x,q0_); q1_=fmaf((P##12).y,sv_.y,q1_); q2_=fmaf((P##12).z,sv_.z,q2_); q3_=fmaf((P##12).w,sv_.w,q3_); \
    sv_=*(const f32x4*)((ST)+52); q0_=fmaf((P##13).x,sv_.x,q0_); q1_=fmaf((P##13).y,sv_.y,q1_); q2_=fmaf((P##13).z,sv_.z,q2_); q3_=fmaf((P##13).w,sv_.w,q3_); \
    sv_=*(const f32x4*)((ST)+56); q0_=fmaf((P##14).x,sv_.x,q0_); q1_=fmaf((P##14).y,sv_.y,q1_); q2_=fmaf((P##14).z,sv_.z,q2_); q3_=fmaf((P##14).w,sv_.w,q3_); \
    sv_=*(const f32x4*)((ST)+60); q0_=fmaf((P##15).x,sv_.x,q0_); q1_=fmaf((P##15).y,sv_.y,q1_); q2_=fmaf((P##15).z,sv_.z,q2_); q3_=fmaf((P##15).w,sv_.w,q3_); \
    OUT = (q0_+q1_)+(q2_+q3_); }

#define LOADW(P, SRC) \
    f32x4 P##0=*(const f32x4*)((SRC)+ 0), P##1=*(const f32x4*)((SRC)+ 4), \
          P##2=*(const f32x4*)((SRC)+ 8), P##3=*(const f32x4*)((SRC)+12), \
          P##4=*(const f32x4*)((SRC)+16), P##5=*(const f32x4*)((SRC)+20), \
          P##6=*(const f32x4*)((SRC)+24), P##7=*(const f32x4*)((SRC)+28), \
          P##8=*(const f32x4*)((SRC)+32), P##9=*(const f32x4*)((SRC)+36), \
          P##10=*(const f32x4*)((SRC)+40), P##11=*(const f32x4*)((SRC)+44), \
          P##12=*(const f32x4*)((SRC)+48), P##13=*(const f32x4*)((SRC)+52), \
          P##14=*(const f32x4*)((SRC)+56), P##15=*(const f32x4*)((SRC)+60); \
    asm volatile("" : "+v"(P##0), "+v"(P##1), "+v"(P##2),  "+v"(P##3), \
                      "+v"(P##4), "+v"(P##5), "+v"(P##6),  "+v"(P##7), \
                      "+v"(P##8), "+v"(P##9), "+v"(P##10), "+v"(P##11), \
                      "+v"(P##12), "+v"(P##13), "+v"(P##14), "+v"(P##15));

// ---------------------------------------------------------------------------
// Kernel B: fused scan+emit, TWO BATCHES PER WG. 32 WGs x 512 thr:
// pair = wg&3 -> batches {2p, 2p+1}; oct = wg>>2 owns rows [oct*64, +64).
// Per batch: round-11 proven layout (lane (w,l): row o = oct*64+w*8+(l>>3),
// k-segment (l&7)*64; shfl_xor(1,2,4)+shfl_xor(8) reduce; kseg==0 publishes;
// wave w != oct polls segment w; sc1 tagged parity double buffer).
// Wt AND Wo slices live in registers (shared across both batches — pairing
// costs zero extra weight regs). Emit for output row s-1 is computed
// in-loop from stt[par] (= states[s-1]) inside the publish->detect latency
// window; the emit kernel and the states[] buffer are DELETED. Final row
// emitted in an epilogue from the tag-2048 exchange.
// ---------------------------------------------------------------------------
__global__ __launch_bounds__(512, 2) void scan_fused_kernel(
    const float* __restrict__ Wt, const float* __restrict__ bt,
    const float* __restrict__ Wo, const float* __restrict__ bo,
    const float* __restrict__ gbuf, const float* __restrict__ cosb,
    const float* __restrict__ sinb, const float* __restrict__ cdbuf,
    uint2* stateTag, float* __restrict__ out, float* __restrict__ finalOut)
{
    const int wg = blockIdx.x;
    const int pair = wg & 3, oct = wg >> 2;
    const int b0 = pair * 2, b1 = b0 + 1;
    const int tid = threadIdx.x;
    const int w = tid >> 6;
    const int l = tid & 63;
    const int kseg = l & 7;
    const int rl = l >> 3;
    const int o = oct * 64 + w * 8 + rl;   // row this lane computes
    const int e = w * 64 + l;              // element wave w polls (w != oct)
    const bool isPub = (kseg == 0);

    __shared__ float stt[2][2][8][68];     // [batch01][parity][seg][elem]

    // register/AGPR-resident weight slices (shared by both batches)
    LOADW(wt, Wt + (size_t)o * DDIM + kseg * 64)
    LOADW(wo, Wo + (size_t)o * DDIM + kseg * 64)
    const float btv = bt[o];
    const float bov = bo[o];

    const float* pg0  = gbuf  + (size_t)b0 * SLEN * 512;
    const float* pcd0 = cdbuf + (size_t)b0 * SLEN * 512;
    const float* pc0  = cosb  + (size_t)b0 * SLEN * 256;
    const float* psn0 = sinb  + (size_t)b0 * SLEN * 256;
    const float* pg1  = gbuf  + (size_t)b1 * SLEN * 512;
    const float* pcd1 = cdbuf + (size_t)b1 * SLEN * 512;
    const float* pc1  = cosb  + (size_t)b1 * SLEN * 256;
    const float* psn1 = sinb  + (size_t)b1 * SLEN * 256;
    float* out0 = out + (size_t)b0 * SLEN * 512;   // og staged here by A
    float* out1 = out + (size_t)b1 * SLEN * 512;

    stt[0][0][w][l] = 0.f;    // S_0 = 0, both batches
    stt[1][0][w][l] = 0.f;

    // gate prologue (publishing lanes; step 0)
    float g0C = 0.f, cd0C = 0.f, c0C = 0.f, sn0C = 0.f;
    float g1C = 0.f, cd1C = 0.f, c1C = 0.f, sn1C = 0.f;
    float og0C = 0.f, og1C = 0.f;   // og[s-1], rotated at each iteration tail
    if (isPub) {
        g0C = pg0[o]; cd0C = pcd0[o]; c0C = pc0[o >> 1]; sn0C = psn0[o >> 1];
        g1C = pg1[o]; cd1C = pcd1[o]; c1C = pc1[o >> 1]; sn1C = psn1[o >> 1];
    }
    __syncthreads();

    for (int s = 0; s < SLEN; ++s) {
        const int par = s & 1;
        const unsigned want = (unsigned)(s + 1);

        // ---- scan matvecs (both batches) ----
        float tA, tB;
        DOT64(wt, &stt[0][par][kseg][0], tA)
        DOT64(wt, &stt[1][par][kseg][0], tB)
        tA += __shfl_xor(tA, 1); tA += __shfl_xor(tA, 2); tA += __shfl_xor(tA, 4);
        tB += __shfl_xor(tB, 1); tB += __shfl_xor(tB, 2); tB += __shfl_xor(tB, 4);
        tA += btv; tB += btv;
        float tpA = __shfl_xor(tA, 8);
        float tpB = __shfl_xor(tB, 8);

        // ---- rotate/gate + publish (earliest; ALWAYS, incl. tag 2048) ----
        if (isPub) {
            float rotA = (rl & 1) ? fmaf(tpA, sn0C, tA * c0C)
                                  : fmaf(tA, c0C, -(tpA * sn0C));
            float nxtA = fmaf(g0C, rotA, (1.f - g0C) * cd0C);
            uint2 uA; uA.x = __float_as_uint(nxtA); uA.y = want;
            st_u64_sc1(&stateTag[((size_t)(par ^ 1) * BNUM + b0) * 512 + o], uA);
            float rotB = (rl & 1) ? fmaf(tpB, sn1C, tB * c1C)
                                  : fmaf(tB, c1C, -(tpB * sn1C));
            float nxtB = fmaf(g1C, rotB, (1.f - g1C) * cd1C);
            uint2 uB; uB.x = __float_as_uint(nxtB); uB.y = want;
            st_u64_sc1(&stateTag[((size_t)(par ^ 1) * BNUM + b1) * 512 + o], uB);
            stt[0][par ^ 1][oct][w * 8 + rl] = nxtA;   // own segment fills
            stt[1][par ^ 1][oct][w * 8 + rl] = nxtB;
            if (s == SLEN - 1) {
                finalOut[b0 * 512 + o] = nxtA;
                finalOut[b1 * 512 + o] = nxtB;
            }
        }

        // ---- fused emit for output row s-1 (stt[par] = states[s-1];
        //      disjoint parity from every iteration-s write) ----
        if (s) {
            float eA, eB;
            DOT64(wo, &stt[0][par][kseg][0], eA)
            DOT64(wo, &stt[1][par][kseg][0], eB)
            eA += __shfl_xor(eA, 1); eA += __shfl_xor(eA, 2); eA += __shfl_xor(eA, 4);
            eB += __shfl_xor(eB, 1); eB += __shfl_xor(eB, 2); eB += __shfl_xor(eB, 4);
            if (isPub) {
                out0[(size_t)(s - 1) * 512 + o] = og0C * (eA + bov);
                out1[(size_t)(s - 1) * 512 + o] = og1C * (eB + bov);
            }
        }

        // ---- polls (both batches; emits above covered peer flight) ----
        if (w != oct) {
            const uint2* ppA = &stateTag[((size_t)(par ^ 1) * BNUM + b0) * 512 + e];
            uint2 uA; int guard = 0;
            do { uA = ld_u64_sc1(ppA); }
            while (uA.y != want && ++guard < (1 << 16));
            stt[0][par ^ 1][w][l] = __uint_as_float(uA.x);
            const uint2* ppB = &stateTag[((size_t)(par ^ 1) * BNUM + b1) * 512 + e];
            uint2 uB; guard = 0;
            do { uB = ld_u64_sc1(ppB); }
            while (uB.y != want && ++guard < (1 << 16));
            stt[1][par ^ 1][w][l] = __uint_as_float(uB.x);
        }

        // ---- prefetch next gates + this step's og (post-poll) ----
        if (isPub) {
            int sp1 = (s + 1) & (SLEN - 1);   // wrap harmlessly at the end
            g0C = pg0[(size_t)sp1 * 512 + o]; cd0C = pcd0[(size_t)sp1 * 512 + o];
            c0C = pc0[(size_t)sp1 * 256 + (o >> 1)]; sn0C = psn0[(size_t)sp1 * 256 + (o >> 1)];
            g1C = pg1[(size_t)sp1 * 512 + o]; cd1C = pcd1[(size_t)sp1 * 512 + o];
            c1C = pc1[(size_t)sp1 * 256 + (o >> 1)]; sn1C = psn1[(size_t)sp1 * 256 + (o >> 1)];
            og0C = out0[(size_t)s * 512 + o];   // og[s], consumed at s+1
            og1C = out1[(size_t)s * 512 + o];
        }
        __syncthreads();   // stt[par^1] complete -> next step
    }

    // ---- epilogue: emit final row (SLEN-1) from S_SLEN in stt[*][0] ----
    {
        float eA, eB;
        DOT64(wo, &stt[0][0][kseg][0], eA)
        DOT64(wo, &stt[1][0][kseg][0], eB)
        eA += __shfl_xor(eA, 1); eA += __shfl_xor(eA, 2); eA += __shfl_xor(eA, 4);
        eB += __shfl_xor(eB, 1); eB += __shfl_xor(eB, 2); eB += __shfl_xor(eB, 4);
        if (isPub) {
            out0[(size_t)(SLEN - 1) * 512 + o] = og0C * (eA + bov);
            out1[(size_t)(SLEN - 1) * 512 + o] = og1C * (eB + bov);
        }
    }
}

// ---------------------------------------------------------------------------
extern "C" void kernel_launch(void* const* d_in, const int* in_sizes, int n_in,
                              void* d_out, int out_size, void* d_ws, size_t ws_size,
                              hipStream_t stream)
{
    const float* x  = (const float*)d_in[0];
    const float* Wu = (const float*)d_in[1];
    const float* bu = (const float*)d_in[2];
    const float* Wt = (const float*)d_in[3];
    const float* bt = (const float*)d_in[4];
    const float* Wa = (const float*)d_in[5];
    const float* ba = (const float*)d_in[6];
    const float* Wc = (const float*)d_in[7];
    const float* bc = (const float*)d_in[8];
    const float* Wg = (const float*)d_in[9];
    const float* bg = (const float*)d_in[10];
    const float* Wo = (const float*)d_in[11];
    const float* bo = (const float*)d_in[12];
    float* out = (float*)d_out;

    // workspace layout (floats)
    float* wsf    = (float*)d_ws;
    float* gbuf   = wsf;                               // 16384*512
    float* cosb   = gbuf   + (size_t)MTOT * 512;       // 16384*256
    float* sinb   = cosb   + (size_t)MTOT * 256;       // 16384*256
    float* cdbuf  = sinb   + (size_t)MTOT * 256;       // 16384*512
    uint2* stateTag = (uint2*)(cdbuf + (size_t)MTOT * 512); // 2*8*512 uint2

    clear_tags_kernel<<<16, 512, 0, stream>>>(stateTag);

    precompute_kernel<<<dim3(14, 128), 256, 0, stream>>>(
        x, Wu, bu, Wa, ba, Wc, bc, Wg, bg,
        gbuf, cosb, sinb, cdbuf, out /* og staged in emitted region */);

    scan_fused_kernel<<<32, 512, 0, stream>>>(
        Wt, bt, Wo, bo, gbuf, cosb, sinb, cdbuf,
        stateTag, out, out + (size_t)MTOT * 512);
}

// Round 16
// 4785.046 us; speedup vs baseline: 1.3087x; 1.3087x over previous
//
#include <hip/hip_runtime.h>
#include <hip/hip_bf16.h>
#include <math.h>

#define SLEN 2048
#define DDIM 512
#define BNUM 8
#define MTOT (BNUM * SLEN)   // 16384

typedef float f32x4 __attribute__((ext_vector_type(4)));
typedef short s16x8 __attribute__((ext_vector_type(8)));   // 8 bf16 (4 VGPRs)

// fp32 -> bf16 (RNE) as raw ushort
__device__ __forceinline__ unsigned short f2bf(float f) {
    unsigned u = __float_as_uint(f);
    u += 0x7FFFu + ((u >> 16) & 1u);
    return (unsigned short)(u >> 16);
}

// ---------------------------------------------------------------------------
// Device-scope (sc1) 8-byte access. Proven facts: sc0 = SE scope (stale
// cross-CU, r8); atomics-as-poll dirty L2 lines -> 7x HBM writeback (r13);
// issue+waitcnt of a comm load must be ONE asm block (r12); >64 weight
// regs/thread breaks compiler residency (r15, VGPR=92 < 128 needed ->
// 512KB/WG/iter L2 re-streaming). sc1 tagged slots = the protocol (r4-r13).
// ---------------------------------------------------------------------------
__device__ __forceinline__ void st_u64_sc1(uint2* p, uint2 v) {
    asm volatile("global_store_dwordx2 %0, %1, off sc1"
                 :: "v"(p), "v"(v) : "memory");
}
__device__ __forceinline__ uint2 ld_u64_sc1(const uint2* p) {
    uint2 v;
    asm volatile("global_load_dwordx2 %0, %1, off sc1\n\ts_waitcnt vmcnt(0)"
                 : "=v"(v) : "v"(p) : "memory");
    return v;
}

// ---------------------------------------------------------------------------
// Kernel 0: clear tag buffer through the SAME sc1 path the scan uses.
// ---------------------------------------------------------------------------
__global__ __launch_bounds__(512) void clear_tags_kernel(uint2* stateTag)
{
    int i = blockIdx.x * 512 + threadIdx.x;
    uint2 z; z.x = 0u; z.y = 0u;
    st_u64_sc1(&stateTag[i], z);
}

// ---------------------------------------------------------------------------
// Kernel A: fused precompute GEMM via bf16 MFMA (round-10, proven).
// ---------------------------------------------------------------------------
__global__ __launch_bounds__(256) void precompute_kernel(
    const float* __restrict__ x,
    const float* __restrict__ Wu, const float* __restrict__ bu,
    const float* __restrict__ Wa, const float* __restrict__ ba,
    const float* __restrict__ Wc, const float* __restrict__ bc,
    const float* __restrict__ Wg, const float* __restrict__ bg,
    float* __restrict__ gbuf, float* __restrict__ cosb,
    float* __restrict__ sinb, float* __restrict__ cdbuf,
    float* __restrict__ ogout)
{
    __shared__ unsigned short As[128 * 40];
    __shared__ unsigned short Bs[128 * 40];

    const int bn = blockIdx.x * 128;      // 0..1791 in steps of 128
    const int bm = blockIdx.y * 128;      // 0..16383

    const float* W; const float* bias; int mode; int dcol;
    if (bn < 512)       { W = Wu; bias = bu; mode = 0; dcol = bn; }
    else if (bn < 768)  { W = Wa; bias = ba; mode = 1; dcol = bn - 512; }
    else if (bn < 1280) { W = Wc; bias = bc; mode = 2; dcol = bn - 768; }
    else                { W = Wg; bias = bg; mode = 3; dcol = bn - 1280; }

    const int tid  = threadIdx.x;
    const int lane = tid & 63, wv = tid >> 6;
    const int wm = wv >> 1, wn = wv & 1;
    const int lr  = lane & 15;
    const int lkb = (lane >> 4) * 8;      // ushort offset of the 8-k group

    f32x4 acc[4][4];
    #pragma unroll
    for (int i = 0; i < 4; ++i)
        #pragma unroll
        for (int j = 0; j < 4; ++j)
            acc[i][j] = (f32x4){0.f, 0.f, 0.f, 0.f};

    const int r = tid >> 1, h = tid & 1;  // staging: row, k-half
    const float* aSrc = x + (size_t)(bm + r) * DDIM + h * 16;
    const float* bSrc = W + (size_t)(dcol + r) * DDIM + h * 16;
    unsigned short* aDst = &As[r * 40 + h * 16];
    unsigned short* bDst = &Bs[r * 40 + h * 16];

    for (int kt = 0; kt < 16; ++kt) {
        {
            float4 fa0 = *(const float4*)(aSrc + 0);
            float4 fa1 = *(const float4*)(aSrc + 4);
            float4 fa2 = *(const float4*)(aSrc + 8);
            float4 fa3 = *(const float4*)(aSrc + 12);
            union { unsigned short u[8]; s16x8 v; } pa0, pa1;
            pa0.u[0]=f2bf(fa0.x); pa0.u[1]=f2bf(fa0.y); pa0.u[2]=f2bf(fa0.z); pa0.u[3]=f2bf(fa0.w);
            pa0.u[4]=f2bf(fa1.x); pa0.u[5]=f2bf(fa1.y); pa0.u[6]=f2bf(fa1.z); pa0.u[7]=f2bf(fa1.w);
            pa1.u[0]=f2bf(fa2.x); pa1.u[1]=f2bf(fa2.y); pa1.u[2]=f2bf(fa2.z); pa1.u[3]=f2bf(fa2.w);
            pa1.u[4]=f2bf(fa3.x); pa1.u[5]=f2bf(fa3.y); pa1.u[6]=f2bf(fa3.z); pa1.u[7]=f2bf(fa3.w);
            *(s16x8*)(aDst + 0) = pa0.v;
            *(s16x8*)(aDst + 8) = pa1.v;

            float4 fb0 = *(const float4*)(bSrc + 0);
            float4 fb1 = *(const float4*)(bSrc + 4);
            float4 fb2 = *(const float4*)(bSrc + 8);
            float4 fb3 = *(const float4*)(bSrc + 12);
            union { unsigned short u[8]; s16x8 v; } pb0, pb1;
            pb0.u[0]=f2bf(fb0.x); pb0.u[1]=f2bf(fb0.y); pb0.u[2]=f2bf(fb0.z); pb0.u[3]=f2bf(fb0.w);
            pb0.u[4]=f2bf(fb1.x); pb0.u[5]=f2bf(fb1.y); pb0.u[6]=f2bf(fb1.z); pb0.u[7]=f2bf(fb1.w);
            pb1.u[0]=f2bf(fb2.x); pb1.u[1]=f2bf(fb2.y); pb1.u[2]=f2bf(fb2.z); pb1.u[3]=f2bf(fb2.w);
            pb1.u[4]=f2bf(fb3.x); pb1.u[5]=f2bf(fb3.y); pb1.u[6]=f2bf(fb3.z); pb1.u[7]=f2bf(fb3.w);
            *(s16x8*)(bDst + 0) = pb0.v;
            *(s16x8*)(bDst + 8) = pb1.v;

            aSrc += 32; bSrc += 32;
        }
        __syncthreads();

        s16x8 af[4], bf[4];
        #pragma unroll
        for (int i = 0; i < 4; ++i)
            af[i] = *(const s16x8*)&As[(wm * 64 + i * 16 + lr) * 40 + lkb];
        #pragma unroll
        for (int j = 0; j < 4; ++j)
            bf[j] = *(const s16x8*)&Bs[(wn * 64 + j * 16 + lr) * 40 + lkb];
        #pragma unroll
        for (int i = 0; i < 4; ++i)
            #pragma unroll
            for (int j = 0; j < 4; ++j)
                acc[i][j] = __builtin_amdgcn_mfma_f32_16x16x32_bf16(
                    af[i], bf[j], acc[i][j], 0, 0, 0);
        __syncthreads();
    }

    // ---- epilogue: bias + activation ----
    const int orow = (lane >> 4) * 4;
    #pragma unroll
    for (int i = 0; i < 4; ++i) {
        #pragma unroll
        for (int j = 0; j < 4; ++j) {
            #pragma unroll
            for (int v = 0; v < 4; ++v) {
                int m  = bm + wm * 64 + i * 16 + orow + v;
                int nc = dcol + wn * 64 + j * 16 + lr;
                float val = acc[i][j][v] + bias[nc];
                if (mode == 0) {
                    gbuf[(size_t)m * 512 + nc] = 1.f / (1.f + expf(-val));
                } else if (mode == 1) {
                    cosb[(size_t)m * 256 + nc] = cosf(val);
                    sinb[(size_t)m * 256 + nc] = sinf(val);
                } else if (mode == 2) {
                    cdbuf[(size_t)m * 512 + nc] = tanhf(val);
                } else {
                    ogout[(size_t)m * 512 + nc] = 1.f / (1.f + expf(-val));
                }
            }
        }
    }
}

// 64-MAC dot of register weight slice P0..P15 with 64 contiguous LDS floats.
// (P##N).x parens required: `P##2.y` pastes against pp-number `2.y` (r14).
#define DOT64(P, ST, OUT) { \
    f32x4 sv_; float q0_=0.f,q1_=0.f,q2_=0.f,q3_=0.f; \
    sv_=*(const f32x4*)((ST)+ 0); q0_=fmaf((P##0).x,sv_.x,q0_); q1_=fmaf((P##0).y,sv_.y,q1_); q2_=fmaf((P##0).z,sv_.z,q2_); q3_=fmaf((P##0).w,sv_.w,q3_); \
    sv_=*(const f32x4*)((ST)+ 4); q0_=fmaf((P##1).x,sv_.x,q0_); q1_=fmaf((P##1).y,sv_.y,q1_); q2_=fmaf((P##1).z,sv_.z,q2_); q3_=fmaf((P##1).w,sv_.w,q3_); \
    sv_=*(const f32x4*)((ST)+ 8); q0_=fmaf((P##2).x,sv_.x,q0_); q1_=fmaf((P##2).y,sv_.y,q1_); q2_=fmaf((P##2).z,sv_.z,q2_); q3_=fmaf((P##2).w,sv_.w,q3_); \
    sv_=*(const f32x4*)((ST)+12); q0_=fmaf((P##3).x,sv_.x,q0_); q1_=fmaf((P##3).y,sv_.y,q1_); q2_=fmaf((P##3).z,sv_.z,q2_); q3_=fmaf((P##3).w,sv_.w,q3_); \
    sv_=*(const f32x4*)((ST)+16); q0_=fmaf((P##4).x,sv_.x,q0_); q1_=fmaf((P##4).y,sv_.y,q1_); q2_=fmaf((P##4).z,sv_.z,q2_); q3_=fmaf((P##4).w,sv_.w,q3_); \
    sv_=*(const f32x4*)((ST)+20); q0_=fmaf((P##5).x,sv_.x,q0_); q1_=fmaf((P##5).y,sv_.y,q1_); q2_=fmaf((P##5).z,sv_.z,q2_); q3_=fmaf((P##5).w,sv_.w,q3_); \
    sv_=*(const f32x4*)((ST)+24); q0_=fmaf((P##6).x,sv_.x,q0_); q1_=fmaf((P##6).y,sv_.y,q1_); q2_=fmaf((P##6).z,sv_.z,q2_); q3_=fmaf((P##6).w,sv_.w,q3_); \
    sv_=*(const f32x4*)((ST)+28); q0_=fmaf((P##7).x,sv_.x,q0_); q1_=fmaf((P##7).y,sv_.y,q1_); q2_=fmaf((P##7).z,sv_.z,q2_); q3_=fmaf((P##7).w,sv_.w,q3_); \
    sv_=*(const f32x4*)((ST)+32); q0_=fmaf((P##8).x,sv_.x,q0_); q1_=fmaf((P##8).y,sv_.y,q1_); q2_=fmaf((P##8).z,sv_.z,q2_); q3_=fmaf((P##8).w,sv_.w,q3_); \
    sv_=*(const f32x4*)((ST)+36); q0_=fmaf((P##9).x,sv_.x,q0_); q1_=fmaf((P##9).y,sv_.y,q1_); q2_=fmaf((P##9).z,sv_.z,q2_); q3_=fmaf((P##9).w,sv_.w,q3_); \
    sv_=*(const f32x4*)((ST)+40); q0_=fmaf((P##10).x,sv_.x,q0_); q1_=fmaf((P##10).y,sv_.y,q1_); q2_=fmaf((P##10).z,sv_.z,q2_); q3_=fmaf((P##10).w,sv_.w,q3_); \
    sv_=*(const f32x4*)((ST)+44); q0_=fmaf((P##11).x,sv_.x,q0_); q1_=fmaf((P##11).y,sv_.y,q1_); q2_=fmaf((P##11).z,sv_.z,q2_); q3_=fmaf((P##11).w,sv_.w,q3_); \
    sv_=*(const f32x4*)((ST)+48); q0_=fmaf((P##12).x,sv_.x,q0_); q1_=fmaf((P##12).y,sv_.y,q1_); q2_=fmaf((P##12).z,sv_.z,q2_); q3_=fmaf((P##12).w,sv_.w,q3_); \
    sv_=*(const f32x4*)((ST)+52); q0_=fmaf((P##13).x,sv_.x,q0_); q1_=fmaf((P##13).y,sv_.y,q1_); q2_=fmaf((P##13).z,sv_.z,q2_); q3_=fmaf((P##13).w,sv_.w,q3_); \
    sv_=*(const f32x4*)((ST)+56); q0_=fmaf((P##14).x,sv_.x,q0_); q1_=fmaf((P##14).y,sv_.y,q1_); q2_=fmaf((P##14).z,sv_.z,q2_); q3_=fmaf((P##14).w,sv_.w,q3_); \
    sv_=*(const f32x4*)((ST)+60); q0_=fmaf((P##15).x,sv_.x,q0_); q1_=fmaf((P##15).y,sv_.y,q1_); q2_=fmaf((P##15).z,sv_.z,q2_); q3_=fmaf((P##15).w,sv_.w,q3_); \
    OUT = (q0_+q1_)+(q2_+q3_); }

#define LOADW(P, SRC) \
    f32x4 P##0=*(const f32x4*)((SRC)+ 0), P##1=*(const f32x4*)((SRC)+ 4), \
          P##2=*(const f32x4*)((SRC)+ 8), P##3=*(const f32x4*)((SRC)+12), \
          P##4=*(const f32x4*)((SRC)+16), P##5=*(const f32x4*)((SRC)+20), \
          P##6=*(const f32x4*)((SRC)+24), P##7=*(const f32x4*)((SRC)+28), \
          P##8=*(const f32x4*)((SRC)+32), P##9=*(const f32x4*)((SRC)+36), \
          P##10=*(const f32x4*)((SRC)+40), P##11=*(const f32x4*)((SRC)+44), \
          P##12=*(const f32x4*)((SRC)+48), P##13=*(const f32x4*)((SRC)+52), \
          P##14=*(const f32x4*)((SRC)+56), P##15=*(const f32x4*)((SRC)+60); \
    asm volatile("" : "+v"(P##0), "+v"(P##1), "+v"(P##2),  "+v"(P##3), \
                      "+v"(P##4), "+v"(P##5), "+v"(P##6),  "+v"(P##7), \
                      "+v"(P##8), "+v"(P##9), "+v"(P##10), "+v"(P##11), \
                      "+v"(P##12), "+v"(P##13), "+v"(P##14), "+v"(P##15));

// ---------------------------------------------------------------------------
// Kernel B: paired scan, TWO BATCHES PER WG, Wt ONLY in registers (64 regs
// — the proven residency budget; r15's 128 broke it). 32 WGs x 512 thr:
// pair = wg&3 -> batches {2p, 2p+1}; oct = wg>>2 owns rows [oct*64, +64).
// Round-11 proven per-batch layout: lane (wave w, lane l): row
// o = oct*64 + w*8 + (l>>3), k-segment (l&7)*64; reduce = shfl_xor(1,2,4)
// + shfl_xor(8); kseg==0 lanes publish; wave w != oct polls segment w.
// Pairing: mvA, mvB, pubA+pubB (early, both in flight), pollA (absorbs the
// LLC detect), pollB (data arrived during pollA -> ~1 fast RT), gates
// post-poll, ONE barrier -> two steps share one latency window.
// ---------------------------------------------------------------------------
__global__ __launch_bounds__(512, 2) void scan_pair_kernel(
    const float* __restrict__ Wt, const float* __restrict__ bt,
    const float* __restrict__ gbuf, const float* __restrict__ cosb,
    const float* __restrict__ sinb, const float* __restrict__ cdbuf,
    float* __restrict__ states, uint2* stateTag,
    float* __restrict__ finalOut)
{
    const int wg = blockIdx.x;
    const int pair = wg & 3, oct = wg >> 2;
    const int b0 = pair * 2, b1 = b0 + 1;
    const int tid = threadIdx.x;
    const int w = tid >> 6;
    const int l = tid & 63;
    const int kseg = l & 7;
    const int rl = l >> 3;
    const int o = oct * 64 + w * 8 + rl;   // row this lane computes
    const int e = w * 64 + l;              // element wave w polls (w != oct)
    const bool isPub = (kseg == 0);

    __shared__ float stt[2][2][8][68];     // [batch01][parity][seg][elem]

    // register/AGPR-resident Wt slice (shared by both batches): 64 regs
    LOADW(wt, Wt + (size_t)o * DDIM + kseg * 64)
    const float btv = bt[o];

    const float* pg0  = gbuf  + (size_t)b0 * SLEN * 512;
    const float* pcd0 = cdbuf + (size_t)b0 * SLEN * 512;
    const float* pc0  = cosb  + (size_t)b0 * SLEN * 256;
    const float* psn0 = sinb  + (size_t)b0 * SLEN * 256;
    const float* pg1  = gbuf  + (size_t)b1 * SLEN * 512;
    const float* pcd1 = cdbuf + (size_t)b1 * SLEN * 512;
    const float* pc1  = cosb  + (size_t)b1 * SLEN * 256;
    const float* psn1 = sinb  + (size_t)b1 * SLEN * 256;
    float* stb0 = states + (size_t)b0 * SLEN * 512;
    float* stb1 = states + (size_t)b1 * SLEN * 512;

    stt[0][0][w][l] = 0.f;    // S_0 = 0, both batches
    stt[1][0][w][l] = 0.f;

    // gate prologue (publishing lanes; step 0)
    float g0C = 0.f, cd0C = 0.f, c0C = 0.f, sn0C = 0.f;
    float g1C = 0.f, cd1C = 0.f, c1C = 0.f, sn1C = 0.f;
    if (isPub) {
        g0C = pg0[o]; cd0C = pcd0[o]; c0C = pc0[o >> 1]; sn0C = psn0[o >> 1];
        g1C = pg1[o]; cd1C = pcd1[o]; c1C = pc1[o >> 1]; sn1C = psn1[o >> 1];
    }
    __syncthreads();

    for (int s = 0; s < SLEN; ++s) {
        const int par = s & 1;
        const unsigned want = (unsigned)(s + 1);

        // ---- scan matvecs (both batches, weights shared) ----
        float tA, tB;
        DOT64(wt, &stt[0][par][kseg][0], tA)
        DOT64(wt, &stt[1][par][kseg][0], tB)
        tA += __shfl_xor(tA, 1); tA += __shfl_xor(tA, 2); tA += __shfl_xor(tA, 4);
        tB += __shfl_xor(tB, 1); tB += __shfl_xor(tB, 2); tB += __shfl_xor(tB, 4);
        tA += btv; tB += btv;
        float tpA = __shfl_xor(tA, 8);
        float tpB = __shfl_xor(tB, 8);

        // ---- rotate/gate + publish BOTH batches (tag stores first) ----
        if (isPub) {
            float rotA = (rl & 1) ? fmaf(tpA, sn0C, tA * c0C)
                                  : fmaf(tA, c0C, -(tpA * sn0C));
            float nxtA = fmaf(g0C, rotA, (1.f - g0C) * cd0C);
            float rotB = (rl & 1) ? fmaf(tpB, sn1C, tB * c1C)
                                  : fmaf(tB, c1C, -(tpB * sn1C));
            float nxtB = fmaf(g1C, rotB, (1.f - g1C) * cd1C);
            if (s + 1 < SLEN) {   // tag SLEN is never polled
                uint2 uA; uA.x = __float_as_uint(nxtA); uA.y = want;
                st_u64_sc1(&stateTag[((size_t)(par ^ 1) * (2 * BNUM) + b0) * 512 + o], uA);
                uint2 uB; uB.x = __float_as_uint(nxtB); uB.y = want;
                st_u64_sc1(&stateTag[((size_t)(par ^ 1) * (2 * BNUM) + b1) * 512 + o], uB);
            }
            stb0[(size_t)s * 512 + o] = nxtA;          // for emit kernel
            stb1[(size_t)s * 512 + o] = nxtB;
            stt[0][par ^ 1][oct][w * 8 + rl] = nxtA;   // own segment fills
            stt[1][par ^ 1][oct][w * 8 + rl] = nxtB;
            if (s == SLEN - 1) {
                finalOut[b0 * 512 + o] = nxtA;
                finalOut[b1 * 512 + o] = nxtB;
            }
        }

        // ---- polls: A absorbs the detect latency, B is ~already there ----
        if (w != oct && s + 1 < SLEN) {
            const uint2* ppA = &stateTag[((size_t)(par ^ 1) * (2 * BNUM) + b0) * 512 + e];
            uint2 uA; int guard = 0;
            do { uA = ld_u64_sc1(ppA); }
            while (uA.y != want && ++guard < (1 << 16));
            stt[0][par ^ 1][w][l] = __uint_as_float(uA.x);
            const uint2* ppB = &stateTag[((size_t)(par ^ 1) * (2 * BNUM) + b1) * 512 + e];
            uint2 uB; guard = 0;
            do { uB = ld_u64_sc1(ppB); }
            while (uB.y != want && ++guard < (1 << 16));
            stt[1][par ^ 1][w][l] = __uint_as_float(uB.x);
        }

        // ---- gate prefetch for s+1 (post-poll; latency covered by the
        //      barrier + next matvecs) ----
        if (isPub) {
            int sp1 = (s + 1) & (SLEN - 1);   // wrap harmlessly at the end
            g0C = pg0[(size_t)sp1 * 512 + o]; cd0C = pcd0[(size_t)sp1 * 512 + o];
            c0C = pc0[(size_t)sp1 * 256 + (o >> 1)]; sn0C = psn0[(size_t)sp1 * 256 + (o >> 1)];
            g1C = pg1[(size_t)sp1 * 512 + o]; cd1C = pcd1[(size_t)sp1 * 512 + o];
            c1C = pc1[(size_t)sp1 * 256 + (o >> 1)]; sn1C = psn1[(size_t)sp1 * 256 + (o >> 1)];
        }
        __syncthreads();   // stt[par^1] complete -> next step
    }
}

// ---------------------------------------------------------------------------
// Kernel C: emitted = og * (states @ Wo^T + bo) via bf16 MFMA (round-10,
// proven). og staged in d_out by kernel A; read then overwritten.
// ---------------------------------------------------------------------------
__global__ __launch_bounds__(256) void emit_kernel(
    const float* __restrict__ states, const float* __restrict__ Wo,
    const float* __restrict__ bo, float* __restrict__ out)
{
    __shared__ unsigned short As[128 * 40];
    __shared__ unsigned short Bs[128 * 40];

    const int bn = blockIdx.x * 128;
    const int bm = blockIdx.y * 128;

    const int tid  = threadIdx.x;
    const int lane = tid & 63, wv = tid >> 6;
    const int wm = wv >> 1, wn = wv & 1;
    const int lr  = lane & 15;
    const int lkb = (lane >> 4) * 8;

    f32x4 acc[4][4];
    #pragma unroll
    for (int i = 0; i < 4; ++i)
        #pragma unroll
        for (int j = 0; j < 4; ++j)
            acc[i][j] = (f32x4){0.f, 0.f, 0.f, 0.f};

    const int r = tid >> 1, h = tid & 1;
    const float* aSrc = states + (size_t)(bm + r) * DDIM + h * 16;
    const float* bSrc = Wo + (size_t)(bn + r) * DDIM + h * 16;
    unsigned short* aDst = &As[r * 40 + h * 16];
    unsigned short* bDst = &Bs[r * 40 + h * 16];

    for (int kt = 0; kt < 16; ++kt) {
        {
            float4 fa0 = *(const float4*)(aSrc + 0);
            float4 fa1 = *(const float4*)(aSrc + 4);
            float4 fa2 = *(const float4*)(aSrc + 8);
            float4 fa3 = *(const float4*)(aSrc + 12);
            union { unsigned short u[8]; s16x8 v; } pa0, pa1;
            pa0.u[0]=f2bf(fa0.x); pa0.u[1]=f2bf(fa0.y); pa0.u[2]=f2bf(fa0.z); pa0.u[3]=f2bf(fa0.w);
            pa0.u[4]=f2bf(fa1.x); pa0.u[5]=f2bf(fa1.y); pa0.u[6]=f2bf(fa1.z); pa0.u[7]=f2bf(fa1.w);
            pa1.u[0]=f2bf(fa2.x); pa1.u[1]=f2bf(fa2.y); pa1.u[2]=f2bf(fa2.z); pa1.u[3]=f2bf(fa2.w);
            pa1.u[4]=f2bf(fa3.x); pa1.u[5]=f2bf(fa3.y); pa1.u[6]=f2bf(fa3.z); pa1.u[7]=f2bf(fa3.w);
            *(s16x8*)(aDst + 0) = pa0.v;
            *(s16x8*)(aDst + 8) = pa1.v;

            float4 fb0 = *(const float4*)(bSrc + 0);
            float4 fb1 = *(const float4*)(bSrc + 4);
            float4 fb2 = *(const float4*)(bSrc + 8);
            float4 fb3 = *(const float4*)(bSrc + 12);
            union { unsigned short u[8]; s16x8 v; } pb0, pb1;
            pb0.u[0]=f2bf(fb0.x); pb0.u[1]=f2bf(fb0.y); pb0.u[2]=f2bf(fb0.z); pb0.u[3]=f2bf(fb0.w);
            pb0.u[4]=f2bf(fb1.x); pb0.u[5]=f2bf(fb1.y); pb0.u[6]=f2bf(fb1.z); pb0.u[7]=f2bf(fb1.w);
            pb1.u[0]=f2bf(fb2.x); pb1.u[1]=f2bf(fb2.y); pb1.u[2]=f2bf(fb2.z); pb1.u[3]=f2bf(fb2.w);
            pb1.u[4]=f2bf(fb3.x); pb1.u[5]=f2bf(fb3.y); pb1.u[6]=f2bf(fb3.z); pb1.u[7]=f2bf(fb3.w);
            *(s16x8*)(bDst + 0) = pb0.v;
            *(s16x8*)(bDst + 8) = pb1.v;

            aSrc += 32; bSrc += 32;
        }
        __syncthreads();

        s16x8 af[4], bf[4];
        #pragma unroll
        for (int i = 0; i < 4; ++i)
            af[i] = *(const s16x8*)&As[(wm * 64 + i * 16 + lr) * 40 + lkb];
        #pragma unroll
        for (int j = 0; j < 4; ++j)
            bf[j] = *(const s16x8*)&Bs[(wn * 64 + j * 16 + lr) * 40 + lkb];
        #pragma unroll
        for (int i = 0; i < 4; ++i)
            #pragma unroll
            for (int j = 0; j < 4; ++j)
                acc[i][j] = __builtin_amdgcn_mfma_f32_16x16x32_bf16(
                    af[i], bf[j], acc[i][j], 0, 0, 0);
        __syncthreads();
    }

    const int orow = (lane >> 4) * 4;
    #pragma unroll
    for (int i = 0; i < 4; ++i) {
        #pragma unroll
        for (int j = 0; j < 4; ++j) {
            #pragma unroll
            for (int v = 0; v < 4; ++v) {
                int m = bm + wm * 64 + i * 16 + orow + v;
                int n = bn + wn * 64 + j * 16 + lr;
                size_t idx = (size_t)m * 512 + n;
                float og = out[idx];
                out[idx] = og * (acc[i][j][v] + bo[n]);
            }
        }
    }
}

// ---------------------------------------------------------------------------
extern "C" void kernel_launch(void* const* d_in, const int* in_sizes, int n_in,
                              void* d_out, int out_size, void* d_ws, size_t ws_size,
                              hipStream_t stream)
{
    const float* x  = (const float*)d_in[0];
    const float* Wu = (const float*)d_in[1];
    const float* bu = (const float*)d_in[2];
    const float* Wt = (const float*)d_in[3];
    const float* bt = (const float*)d_in[4];
    const float* Wa = (const float*)d_in[5];
    const float* ba = (const float*)d_in[6];
    const float* Wc = (const float*)d_in[7];
    const float* bc = (const float*)d_in[8];
    const float* Wg = (const float*)d_in[9];
    const float* bg = (const float*)d_in[10];
    const float* Wo = (const float*)d_in[11];
    const float* bo = (const float*)d_in[12];
    float* out = (float*)d_out;

    // workspace layout (floats)
    float* wsf    = (float*)d_ws;
    float* gbuf   = wsf;                               // 16384*512
    float* cosb   = gbuf   + (size_t)MTOT * 512;       // 16384*256
    float* sinb   = cosb   + (size_t)MTOT * 256;       // 16384*256
    float* cdbuf  = sinb   + (size_t)MTOT * 256;       // 16384*512
    float* states = cdbuf  + (size_t)MTOT * 512;       // 16384*512
    uint2* stateTag = (uint2*)(states + (size_t)MTOT * 512); // 2*16*512 uint2

    clear_tags_kernel<<<32, 512, 0, stream>>>(stateTag);

    precompute_kernel<<<dim3(14, 128), 256, 0, stream>>>(
        x, Wu, bu, Wa, ba, Wc, bc, Wg, bg,
        gbuf, cosb, sinb, cdbuf, out /* og staged in emitted region */);

    scan_pair_kernel<<<32, 512, 0, stream>>>(
        Wt, bt, gbuf, cosb, sinb, cdbuf,
        states, stateTag, out + (size_t)MTOT * 512);

    emit_kernel<<<dim3(4, 128), 256, 0, stream>>>(states, Wo, bo, out);
}

// Round 17
// 3856.958 us; speedup vs baseline: 1.6236x; 1.2406x over previous
//
#include <hip/hip_runtime.h>
#include <hip/hip_bf16.h>
#include <math.h>

#define SLEN 2048
#define DDIM 512
#define BNUM 8
#define MTOT (BNUM * SLEN)   // 16384

typedef float f32x4 __attribute__((ext_vector_type(4)));
typedef short s16x8 __attribute__((ext_vector_type(8)));   // 8 bf16 (4 VGPRs)

// fp32 -> bf16 (RNE) as raw ushort
__device__ __forceinline__ unsigned short f2bf(float f) {
    unsigned u = __float_as_uint(f);
    u += 0x7FFFu + ((u >> 16) & 1u);
    return (unsigned short)(u >> 16);
}

// ---------------------------------------------------------------------------
// Device-scope (sc1) 8-byte access. Proven: sc0 = SE scope (r8); L2 atomics
// as poll = 7x HBM writeback + serialization (r13); issue+waitcnt must be
// ONE asm block (r12); pairing batches is useless — batches are already
// parallel across WGs (r16); pinned weights live in AGPRs, 64/thread is the
// budget (r15). sc1 tagged {value, tag} slots = the protocol (r4-r13).
// ---------------------------------------------------------------------------
__device__ __forceinline__ void st_u64_sc1(uint2* p, uint2 v) {
    asm volatile("global_store_dwordx2 %0, %1, off sc1"
                 :: "v"(p), "v"(v) : "memory");
}
__device__ __forceinline__ uint2 ld_u64_sc1(const uint2* p) {
    uint2 v;
    asm volatile("global_load_dwordx2 %0, %1, off sc1\n\ts_waitcnt vmcnt(0)"
                 : "=v"(v) : "v"(p) : "memory");
    return v;
}

// ---------------------------------------------------------------------------
// Kernel 0: clear tag buffer through the SAME sc1 path the scan uses.
// ---------------------------------------------------------------------------
__global__ __launch_bounds__(512) void clear_tags_kernel(uint2* stateTag)
{
    int i = blockIdx.x * 512 + threadIdx.x;
    uint2 z; z.x = 0u; z.y = 0u;
    st_u64_sc1(&stateTag[i], z);
}

// ---------------------------------------------------------------------------
// Kernel A: fused precompute GEMM via bf16 MFMA (round-10, proven).
// ---------------------------------------------------------------------------
__global__ __launch_bounds__(256) void precompute_kernel(
    const float* __restrict__ x,
    const float* __restrict__ Wu, const float* __restrict__ bu,
    const float* __restrict__ Wa, const float* __restrict__ ba,
    const float* __restrict__ Wc, const float* __restrict__ bc,
    const float* __restrict__ Wg, const float* __restrict__ bg,
    float* __restrict__ gbuf, float* __restrict__ cosb,
    float* __restrict__ sinb, float* __restrict__ cdbuf,
    float* __restrict__ ogout)
{
    __shared__ unsigned short As[128 * 40];
    __shared__ unsigned short Bs[128 * 40];

    const int bn = blockIdx.x * 128;      // 0..1791 in steps of 128
    const int bm = blockIdx.y * 128;      // 0..16383

    const float* W; const float* bias; int mode; int dcol;
    if (bn < 512)       { W = Wu; bias = bu; mode = 0; dcol = bn; }
    else if (bn < 768)  { W = Wa; bias = ba; mode = 1; dcol = bn - 512; }
    else if (bn < 1280) { W = Wc; bias = bc; mode = 2; dcol = bn - 768; }
    else                { W = Wg; bias = bg; mode = 3; dcol = bn - 1280; }

    const int tid  = threadIdx.x;
    const int lane = tid & 63, wv = tid >> 6;
    const int wm = wv >> 1, wn = wv & 1;
    const int lr  = lane & 15;
    const int lkb = (lane >> 4) * 8;      // ushort offset of the 8-k group

    f32x4 acc[4][4];
    #pragma unroll
    for (int i = 0; i < 4; ++i)
        #pragma unroll
        for (int j = 0; j < 4; ++j)
            acc[i][j] = (f32x4){0.f, 0.f, 0.f, 0.f};

    const int r = tid >> 1, h = tid & 1;  // staging: row, k-half
    const float* aSrc = x + (size_t)(bm + r) * DDIM + h * 16;
    const float* bSrc = W + (size_t)(dcol + r) * DDIM + h * 16;
    unsigned short* aDst = &As[r * 40 + h * 16];
    unsigned short* bDst = &Bs[r * 40 + h * 16];

    for (int kt = 0; kt < 16; ++kt) {
        {
            float4 fa0 = *(const float4*)(aSrc + 0);
            float4 fa1 = *(const float4*)(aSrc + 4);
            float4 fa2 = *(const float4*)(aSrc + 8);
            float4 fa3 = *(const float4*)(aSrc + 12);
            union { unsigned short u[8]; s16x8 v; } pa0, pa1;
            pa0.u[0]=f2bf(fa0.x); pa0.u[1]=f2bf(fa0.y); pa0.u[2]=f2bf(fa0.z); pa0.u[3]=f2bf(fa0.w);
            pa0.u[4]=f2bf(fa1.x); pa0.u[5]=f2bf(fa1.y); pa0.u[6]=f2bf(fa1.z); pa0.u[7]=f2bf(fa1.w);
            pa1.u[0]=f2bf(fa2.x); pa1.u[1]=f2bf(fa2.y); pa1.u[2]=f2bf(fa2.z); pa1.u[3]=f2bf(fa2.w);
            pa1.u[4]=f2bf(fa3.x); pa1.u[5]=f2bf(fa3.y); pa1.u[6]=f2bf(fa3.z); pa1.u[7]=f2bf(fa3.w);
            *(s16x8*)(aDst + 0) = pa0.v;
            *(s16x8*)(aDst + 8) = pa1.v;

            float4 fb0 = *(const float4*)(bSrc + 0);
            float4 fb1 = *(const float4*)(bSrc + 4);
            float4 fb2 = *(const float4*)(bSrc + 8);
            float4 fb3 = *(const float4*)(bSrc + 12);
            union { unsigned short u[8]; s16x8 v; } pb0, pb1;
            pb0.u[0]=f2bf(fb0.x); pb0.u[1]=f2bf(fb0.y); pb0.u[2]=f2bf(fb0.z); pb0.u[3]=f2bf(fb0.w);
            pb0.u[4]=f2bf(fb1.x); pb0.u[5]=f2bf(fb1.y); pb0.u[6]=f2bf(fb1.z); pb0.u[7]=f2bf(fb1.w);
            pb1.u[0]=f2bf(fb2.x); pb1.u[1]=f2bf(fb2.y); pb1.u[2]=f2bf(fb2.z); pb1.u[3]=f2bf(fb2.w);
            pb1.u[4]=f2bf(fb3.x); pb1.u[5]=f2bf(fb3.y); pb1.u[6]=f2bf(fb3.z); pb1.u[7]=f2bf(fb3.w);
            *(s16x8*)(bDst + 0) = pb0.v;
            *(s16x8*)(bDst + 8) = pb1.v;

            aSrc += 32; bSrc += 32;
        }
        __syncthreads();

        s16x8 af[4], bf[4];
        #pragma unroll
        for (int i = 0; i < 4; ++i)
            af[i] = *(const s16x8*)&As[(wm * 64 + i * 16 + lr) * 40 + lkb];
        #pragma unroll
        for (int j = 0; j < 4; ++j)
            bf[j] = *(const s16x8*)&Bs[(wn * 64 + j * 16 + lr) * 40 + lkb];
        #pragma unroll
        for (int i = 0; i < 4; ++i)
            #pragma unroll
            for (int j = 0; j < 4; ++j)
                acc[i][j] = __builtin_amdgcn_mfma_f32_16x16x32_bf16(
                    af[i], bf[j], acc[i][j], 0, 0, 0);
        __syncthreads();
    }

    // ---- epilogue: bias + activation ----
    const int orow = (lane >> 4) * 4;
    #pragma unroll
    for (int i = 0; i < 4; ++i) {
        #pragma unroll
        for (int j = 0; j < 4; ++j) {
            #pragma unroll
            for (int v = 0; v < 4; ++v) {
                int m  = bm + wm * 64 + i * 16 + orow + v;
                int nc = dcol + wn * 64 + j * 16 + lr;
                float val = acc[i][j][v] + bias[nc];
                if (mode == 0) {
                    gbuf[(size_t)m * 512 + nc] = 1.f / (1.f + expf(-val));
                } else if (mode == 1) {
                    cosb[(size_t)m * 256 + nc] = cosf(val);
                    sinb[(size_t)m * 256 + nc] = sinf(val);
                } else if (mode == 2) {
                    cdbuf[(size_t)m * 512 + nc] = tanhf(val);
                } else {
                    ogout[(size_t)m * 512 + nc] = 1.f / (1.f + expf(-val));
                }
            }
        }
    }
}

// 64-MAC dot of register weight slice P0..P15 with 64 contiguous LDS floats.
// (P##N).x parens required: `P##2.y` pastes against pp-number `2.y` (r14).
#define DOT64(P, ST, OUT) { \
    f32x4 sv_; float q0_=0.f,q1_=0.f,q2_=0.f,q3_=0.f; \
    sv_=*(const f32x4*)((ST)+ 0); q0_=fmaf((P##0).x,sv_.x,q0_); q1_=fmaf((P##0).y,sv_.y,q1_); q2_=fmaf((P##0).z,sv_.z,q2_); q3_=fmaf((P##0).w,sv_.w,q3_); \
    sv_=*(const f32x4*)((ST)+ 4); q0_=fmaf((P##1).x,sv_.x,q0_); q1_=fmaf((P##1).y,sv_.y,q1_); q2_=fmaf((P##1).z,sv_.z,q2_); q3_=fmaf((P##1).w,sv_.w,q3_); \
    sv_=*(const f32x4*)((ST)+ 8); q0_=fmaf((P##2).x,sv_.x,q0_); q1_=fmaf((P##2).y,sv_.y,q1_); q2_=fmaf((P##2).z,sv_.z,q2_); q3_=fmaf((P##2).w,sv_.w,q3_); \
    sv_=*(const f32x4*)((ST)+12); q0_=fmaf((P##3).x,sv_.x,q0_); q1_=fmaf((P##3).y,sv_.y,q1_); q2_=fmaf((P##3).z,sv_.z,q2_); q3_=fmaf((P##3).w,sv_.w,q3_); \
    sv_=*(const f32x4*)((ST)+16); q0_=fmaf((P##4).x,sv_.x,q0_); q1_=fmaf((P##4).y,sv_.y,q1_); q2_=fmaf((P##4).z,sv_.z,q2_); q3_=fmaf((P##4).w,sv_.w,q3_); \
    sv_=*(const f32x4*)((ST)+20); q0_=fmaf((P##5).x,sv_.x,q0_); q1_=fmaf((P##5).y,sv_.y,q1_); q2_=fmaf((P##5).z,sv_.z,q2_); q3_=fmaf((P##5).w,sv_.w,q3_); \
    sv_=*(const f32x4*)((ST)+24); q0_=fmaf((P##6).x,sv_.x,q0_); q1_=fmaf((P##6).y,sv_.y,q1_); q2_=fmaf((P##6).z,sv_.z,q2_); q3_=fmaf((P##6).w,sv_.w,q3_); \
    sv_=*(const f32x4*)((ST)+28); q0_=fmaf((P##7).x,sv_.x,q0_); q1_=fmaf((P##7).y,sv_.y,q1_); q2_=fmaf((P##7).z,sv_.z,q2_); q3_=fmaf((P##7).w,sv_.w,q3_); \
    sv_=*(const f32x4*)((ST)+32); q0_=fmaf((P##8).x,sv_.x,q0_); q1_=fmaf((P##8).y,sv_.y,q1_); q2_=fmaf((P##8).z,sv_.z,q2_); q3_=fmaf((P##8).w,sv_.w,q3_); \
    sv_=*(const f32x4*)((ST)+36); q0_=fmaf((P##9).x,sv_.x,q0_); q1_=fmaf((P##9).y,sv_.y,q1_); q2_=fmaf((P##9).z,sv_.z,q2_); q3_=fmaf((P##9).w,sv_.w,q3_); \
    sv_=*(const f32x4*)((ST)+40); q0_=fmaf((P##10).x,sv_.x,q0_); q1_=fmaf((P##10).y,sv_.y,q1_); q2_=fmaf((P##10).z,sv_.z,q2_); q3_=fmaf((P##10).w,sv_.w,q3_); \
    sv_=*(const f32x4*)((ST)+44); q0_=fmaf((P##11).x,sv_.x,q0_); q1_=fmaf((P##11).y,sv_.y,q1_); q2_=fmaf((P##11).z,sv_.z,q2_); q3_=fmaf((P##11).w,sv_.w,q3_); \
    sv_=*(const f32x4*)((ST)+48); q0_=fmaf((P##12).x,sv_.x,q0_); q1_=fmaf((P##12).y,sv_.y,q1_); q2_=fmaf((P##12).z,sv_.z,q2_); q3_=fmaf((P##12).w,sv_.w,q3_); \
    sv_=*(const f32x4*)((ST)+52); q0_=fmaf((P##13).x,sv_.x,q0_); q1_=fmaf((P##13).y,sv_.y,q1_); q2_=fmaf((P##13).z,sv_.z,q2_); q3_=fmaf((P##13).w,sv_.w,q3_); \
    sv_=*(const f32x4*)((ST)+56); q0_=fmaf((P##14).x,sv_.x,q0_); q1_=fmaf((P##14).y,sv_.y,q1_); q2_=fmaf((P##14).z,sv_.z,q2_); q3_=fmaf((P##14).w,sv_.w,q3_); \
    sv_=*(const f32x4*)((ST)+60); q0_=fmaf((P##15).x,sv_.x,q0_); q1_=fmaf((P##15).y,sv_.y,q1_); q2_=fmaf((P##15).z,sv_.z,q2_); q3_=fmaf((P##15).w,sv_.w,q3_); \
    OUT = (q0_+q1_)+(q2_+q3_); }

#define LOADW(P, SRC) \
    f32x4 P##0=*(const f32x4*)((SRC)+ 0), P##1=*(const f32x4*)((SRC)+ 4), \
          P##2=*(const f32x4*)((SRC)+ 8), P##3=*(const f32x4*)((SRC)+12), \
          P##4=*(const f32x4*)((SRC)+16), P##5=*(const f32x4*)((SRC)+20), \
          P##6=*(const f32x4*)((SRC)+24), P##7=*(const f32x4*)((SRC)+28), \
          P##8=*(const f32x4*)((SRC)+32), P##9=*(const f32x4*)((SRC)+36), \
          P##10=*(const f32x4*)((SRC)+40), P##11=*(const f32x4*)((SRC)+44), \
          P##12=*(const f32x4*)((SRC)+48), P##13=*(const f32x4*)((SRC)+52), \
          P##14=*(const f32x4*)((SRC)+56), P##15=*(const f32x4*)((SRC)+60); \
    asm volatile("" : "+v"(P##0), "+v"(P##1), "+v"(P##2),  "+v"(P##3), \
                      "+v"(P##4), "+v"(P##5), "+v"(P##6),  "+v"(P##7), \
                      "+v"(P##8), "+v"(P##9), "+v"(P##10), "+v"(P##11), \
                      "+v"(P##12), "+v"(P##13), "+v"(P##14), "+v"(P##15));

// ---------------------------------------------------------------------------
// Kernel B: sequential scan, round-11 proven structure + clean-poll
// reorder. 64 WGs x 512 thr: b = wg&7, oct = wg>>3 owns rows [oct*64, +64).
// Lane (wave w, lane l): row o = oct*64 + w*8 + (l>>3), k-segment (l&7)*64
// (64 fp32 weights in VGPR/AGPR). Reduce = shfl_xor(1,2,4) + shfl_xor(8).
// kseg==0 lanes publish; wave w != oct polls segment w; sc1 tagged parity
// double buffer; ONE __syncthreads per step.
// ROUND-17 FIX: in r11, publisher lanes issued 4 HBM gate loads + the
// states store BEFORE the poll; pollers share those waves, so the poll's
// vmcnt(0) drained ~900cy of HBM latency on every step's detect path.
// Now only the 8B tag publish precedes the poll; states store, finalOut,
// and gate prefetch all move AFTER the poll (their latency hides under the
// barrier + next matvec, and any residue overlaps the next detect flight).
// ---------------------------------------------------------------------------
__global__ __launch_bounds__(512, 2) void scan_kernel(
    const float* __restrict__ Wt, const float* __restrict__ bt,
    const float* __restrict__ gbuf, const float* __restrict__ cosb,
    const float* __restrict__ sinb, const float* __restrict__ cdbuf,
    float* __restrict__ states, uint2* stateTag,
    float* __restrict__ finalOut)
{
    const int wg = blockIdx.x;
    const int b = wg & 7, oct = wg >> 3;
    const int tid = threadIdx.x;
    const int w = tid >> 6;
    const int l = tid & 63;
    const int kseg = l & 7;
    const int rl = l >> 3;
    const int o = oct * 64 + w * 8 + rl;   // row this lane computes
    const int e = w * 64 + l;              // element wave w polls (w != oct)
    const bool isPub = (kseg == 0);

    __shared__ float stt[2][8][68];        // [parity][segment][element]

    // register/AGPR-resident weight slice: Wt[o][kseg*64 .. +64)
    LOADW(wt, Wt + (size_t)o * DDIM + kseg * 64)
    const float btv = bt[o];

    const float* pg  = gbuf  + (size_t)b * SLEN * 512;
    const float* pcd = cdbuf + (size_t)b * SLEN * 512;
    const float* pc  = cosb  + (size_t)b * SLEN * 256;
    const float* psn = sinb  + (size_t)b * SLEN * 256;
    float* stb = states + (size_t)b * SLEN * 512;

    stt[0][w][l] = 0.f;    // S_0 = 0

    // gate prologue (publishing lanes; step 0)
    float gC = 0.f, cdC = 0.f, cC = 0.f, snC = 0.f;
    if (isPub) {
        gC  = pg [o];
        cdC = pcd[o];
        cC  = pc [o >> 1];
        snC = psn[o >> 1];
    }
    __syncthreads();

    for (int s = 0; s < SLEN; ++s) {
        const int par = s & 1;
        const unsigned want = (unsigned)(s + 1);

        // ---- matvec over k-segment + reduce ----
        float t;
        DOT64(wt, &stt[par][kseg][0], t)
        t += __shfl_xor(t, 1);
        t += __shfl_xor(t, 2);
        t += __shfl_xor(t, 4);     // 8-lane group holds the full dot
        t += btv;
        float tp = __shfl_xor(t, 8);   // partner row (rl ^ 1)

        // ---- rotate/gate + tag publish (the ONLY pre-poll VMEM op) ----
        float nxt = 0.f;
        if (isPub) {
            float rot = (rl & 1) ? fmaf(tp, snC, t * cC)
                                 : fmaf(t, cC, -(tp * snC));
            nxt = fmaf(gC, rot, (1.f - gC) * cdC);
            if (s + 1 < SLEN) {   // tag SLEN is never polled
                uint2 u; u.x = __float_as_uint(nxt); u.y = want;
                st_u64_sc1(&stateTag[((size_t)(par ^ 1) * BNUM + b) * 512 + o], u);
            }
            stt[par ^ 1][oct][w * 8 + rl] = nxt;   // own segment fill (LDS)
        }

        // ---- poll segment w for step s+1 (clean VMEM queue except the
        //      8B tag store, whose ack < first poll RT) ----
        if (w != oct && s + 1 < SLEN) {
            const uint2* pp = &stateTag[((size_t)(par ^ 1) * BNUM + b) * 512 + e];
            uint2 u; int guard = 0;
            do { u = ld_u64_sc1(pp); }
            while (u.y != want && ++guard < (1 << 16));
            stt[par ^ 1][w][l] = __uint_as_float(u.x);
        }

        // ---- post-poll: states store, finalOut, gate prefetch for s+1 ----
        if (isPub) {
            stb[(size_t)s * 512 + o] = nxt;          // for emit kernel
            if (s == SLEN - 1) finalOut[b * 512 + o] = nxt;
            int sp1 = (s + 1) & (SLEN - 1);          // wrap harmlessly at end
            gC  = pg [(size_t)sp1 * 512 + o];
            cdC = pcd[(size_t)sp1 * 512 + o];
            cC  = pc [(size_t)sp1 * 256 + (o >> 1)];
            snC = psn[(size_t)sp1 * 256 + (o >> 1)];
        }
        __syncthreads();   // stt[par^1] complete -> next step's compute
    }
}

// ---------------------------------------------------------------------------
// Kernel C: emitted = og * (states @ Wo^T + bo) via bf16 MFMA (round-10,
// proven). og staged in d_out by kernel A; read then overwritten.
// ---------------------------------------------------------------------------
__global__ __launch_bounds__(256) void emit_kernel(
    const float* __restrict__ states, const float* __restrict__ Wo,
    const float* __restrict__ bo, float* __restrict__ out)
{
    __shared__ unsigned short As[128 * 40];
    __shared__ unsigned short Bs[128 * 40];

    const int bn = blockIdx.x * 128;
    const int bm = blockIdx.y * 128;

    const int tid  = threadIdx.x;
    const int lane = tid & 63, wv = tid >> 6;
    const int wm = wv >> 1, wn = wv & 1;
    const int lr  = lane & 15;
    const int lkb = (lane >> 4) * 8;

    f32x4 acc[4][4];
    #pragma unroll
    for (int i = 0; i < 4; ++i)
        #pragma unroll
        for (int j = 0; j < 4; ++j)
            acc[i][j] = (f32x4){0.f, 0.f, 0.f, 0.f};

    const int r = tid >> 1, h = tid & 1;
    const float* aSrc = states + (size_t)(bm + r) * DDIM + h * 16;
    const float* bSrc = Wo + (size_t)(bn + r) * DDIM + h * 16;
    unsigned short* aDst = &As[r * 40 + h * 16];
    unsigned short* bDst = &Bs[r * 40 + h * 16];

    for (int kt = 0; kt < 16; ++kt) {
        {
            float4 fa0 = *(const float4*)(aSrc + 0);
            float4 fa1 = *(const float4*)(aSrc + 4);
            float4 fa2 = *(const float4*)(aSrc + 8);
            float4 fa3 = *(const float4*)(aSrc + 12);
            union { unsigned short u[8]; s16x8 v; } pa0, pa1;
            pa0.u[0]=f2bf(fa0.x); pa0.u[1]=f2bf(fa0.y); pa0.u[2]=f2bf(fa0.z); pa0.u[3]=f2bf(fa0.w);
            pa0.u[4]=f2bf(fa1.x); pa0.u[5]=f2bf(fa1.y); pa0.u[6]=f2bf(fa1.z); pa0.u[7]=f2bf(fa1.w);
            pa1.u[0]=f2bf(fa2.x); pa1.u[1]=f2bf(fa2.y); pa1.u[2]=f2bf(fa2.z); pa1.u[3]=f2bf(fa2.w);
            pa1.u[4]=f2bf(fa3.x); pa1.u[5]=f2bf(fa3.y); pa1.u[6]=f2bf(fa3.z); pa1.u[7]=f2bf(fa3.w);
            *(s16x8*)(aDst + 0) = pa0.v;
            *(s16x8*)(aDst + 8) = pa1.v;

            float4 fb0 = *(const float4*)(bSrc + 0);
            float4 fb1 = *(const float4*)(bSrc + 4);
            float4 fb2 = *(const float4*)(bSrc + 8);
            float4 fb3 = *(const float4*)(bSrc + 12);
            union { unsigned short u[8]; s16x8 v; } pb0, pb1;
            pb0.u[0]=f2bf(fb0.x); pb0.u[1]=f2bf(fb0.y); pb0.u[2]=f2bf(fb0.z); pb0.u[3]=f2bf(fb0.w);
            pb0.u[4]=f2bf(fb1.x); pb0.u[5]=f2bf(fb1.y); pb0.u[6]=f2bf(fb1.z); pb0.u[7]=f2bf(fb1.w);
            pb1.u[0]=f2bf(fb2.x); pb1.u[1]=f2bf(fb2.y); pb1.u[2]=f2bf(fb2.z); pb1.u[3]=f2bf(fb2.w);
            pb1.u[4]=f2bf(fb3.x); pb1.u[5]=f2bf(fb3.y); pb1.u[6]=f2bf(fb3.z); pb1.u[7]=f2bf(fb3.w);
            *(s16x8*)(bDst + 0) = pb0.v;
            *(s16x8*)(bDst + 8) = pb1.v;

            aSrc += 32; bSrc += 32;
        }
        __syncthreads();

        s16x8 af[4], bf[4];
        #pragma unroll
        for (int i = 0; i < 4; ++i)
            af[i] = *(const s16x8*)&As[(wm * 64 + i * 16 + lr) * 40 + lkb];
        #pragma unroll
        for (int j = 0; j < 4; ++j)
            bf[j] = *(const s16x8*)&Bs[(wn * 64 + j * 16 + lr) * 40 + lkb];
        #pragma unroll
        for (int i = 0; i < 4; ++i)
            #pragma unroll
            for (int j = 0; j < 4; ++j)
                acc[i][j] = __builtin_amdgcn_mfma_f32_16x16x32_bf16(
                    af[i], bf[j], acc[i][j], 0, 0, 0);
        __syncthreads();
    }

    const int orow = (lane >> 4) * 4;
    #pragma unroll
    for (int i = 0; i < 4; ++i) {
        #pragma unroll
        for (int j = 0; j < 4; ++j) {
            #pragma unroll
            for (int v = 0; v < 4; ++v) {
                int m = bm + wm * 64 + i * 16 + orow + v;
                int n = bn + wn * 64 + j * 16 + lr;
                size_t idx = (size_t)m * 512 + n;
                float og = out[idx];
                out[idx] = og * (acc[i][j][v] + bo[n]);
            }
        }
    }
}

// ---------------------------------------------------------------------------
extern "C" void kernel_launch(void* const* d_in, const int* in_sizes, int n_in,
                              void* d_out, int out_size, void* d_ws, size_t ws_size,
                              hipStream_t stream)
{
    const float* x  = (const float*)d_in[0];
    const float* Wu = (const float*)d_in[1];
    const float* bu = (const float*)d_in[2];
    const float* Wt = (const float*)d_in[3];
    const float* bt = (const float*)d_in[4];
    const float* Wa = (const float*)d_in[5];
    const float* ba = (const float*)d_in[6];
    const float* Wc = (const float*)d_in[7];
    const float* bc = (const float*)d_in[8];
    const float* Wg = (const float*)d_in[9];
    const float* bg = (const float*)d_in[10];
    const float* Wo = (const float*)d_in[11];
    const float* bo = (const float*)d_in[12];
    float* out = (float*)d_out;

    // workspace layout (floats)
    float* wsf    = (float*)d_ws;
    float* gbuf   = wsf;                               // 16384*512
    float* cosb   = gbuf   + (size_t)MTOT * 512;       // 16384*256
    float* sinb   = cosb   + (size_t)MTOT * 256;       // 16384*256
    float* cdbuf  = sinb   + (size_t)MTOT * 256;       // 16384*512
    float* states = cdbuf  + (size_t)MTOT * 512;       // 16384*512
    uint2* stateTag = (uint2*)(states + (size_t)MTOT * 512); // 2*8*512 uint2

    clear_tags_kernel<<<16, 512, 0, stream>>>(stateTag);

    precompute_kernel<<<dim3(14, 128), 256, 0, stream>>>(
        x, Wu, bu, Wa, ba, Wc, bc, Wg, bg,
        gbuf, cosb, sinb, cdbuf, out /* og staged in emitted region */);

    scan_kernel<<<64, 512, 0, stream>>>(
        Wt, bt, gbuf, cosb, sinb, cdbuf,
        states, stateTag, out + (size_t)MTOT * 512);

    emit_kernel<<<dim3(4, 128), 256, 0, stream>>>(states, Wo, bo, out);
}